// Round 11
// baseline (32.213 us; speedup 1.0000x reference)
//
#include <hip/hip_runtime.h>

typedef float f32x4 __attribute__((ext_vector_type(4)));

// Problem constants: x [B,C,T] fp32 -> out [B,C,T] fp32.
#define B_ 32
#define C_ 256
#define T_ 2048
#define NR 4           // rows per wave, software-pipelined (double-buffered LDS)

// R5:  plain stores (L2 write-combining), never nontemporal.
// R7:  strided global loads cap ~2.6 TB/s -> stage rows via global_load_lds.
// R8:  XOR-swizzled b128 LDS reads conflict-free.
// R9:  residency not the limiter.
// R10: coalesced stores via LDS round-trip: 40->31 us. Scatter eliminated.
// R11: pipeline NR=4 rows/wave, counted vmcnt (8/16/16/8) so stage(i+1) and
//      stores(i-1) stay in flight under row i's compute.

#define STEP(X0, XP1, O) { \
    float y = w0 * xm1;  y = y + w1 * (X0);  y = y + w2 * (XP1); \
    y = y + bb;  y = y * inv;  y = y + add; \
    float dv = (y - v) * 0.5f;  v = v + dv; \
    float s = (v >= 1.0f) ? 1.0f : 0.0f; \
    (O) = s + (X0); \
    v = (v >= 1.0f) ? 0.0f : v; \
    xm1 = (X0); }

#define Q4(BV, NX, O) \
    STEP(BV.x, BV.y, O.x) STEP(BV.y, BV.z, O.y) \
    STEP(BV.z, BV.w, O.z) STEP(BV.w, NX,   O.w)

#define LDPH(p0,p1,p2,p3,p4,p5,p6,p7, GC) { \
    const int _m = ((GC) >> 3) & 7; \
    const float* _bp = wl + ((GC) << 2); \
    p0 = *(const f32x4*)(_bp + ((0 ^ _m) << 2)); \
    p1 = *(const f32x4*)(_bp + ((1 ^ _m) << 2)); \
    p2 = *(const f32x4*)(_bp + ((2 ^ _m) << 2)); \
    p3 = *(const f32x4*)(_bp + ((3 ^ _m) << 2)); \
    p4 = *(const f32x4*)(_bp + ((4 ^ _m) << 2)); \
    p5 = *(const f32x4*)(_bp + ((5 ^ _m) << 2)); \
    p6 = *(const f32x4*)(_bp + ((6 ^ _m) << 2)); \
    p7 = *(const f32x4*)(_bp + ((7 ^ _m) << 2)); }

#define PHC(r0,r1,r2,r3,r4,r5,r6,r7, PEEK) { \
    f32x4 _d; \
    Q4(r0, r1.x, _d) Q4(r1, r2.x, _d) Q4(r2, r3.x, _d) Q4(r3, r4.x, _d) \
    Q4(r4, r5.x, _d) Q4(r5, r6.x, _d) Q4(r6, r7.x, _d) Q4(r7, (PEEK), _d) }

__device__ __forceinline__ int swzg(int g) { return g ^ ((g >> 3) & 7); }

typedef __attribute__((address_space(1))) const unsigned int GBUF;
typedef __attribute__((address_space(3))) unsigned int LBUF;

// Issue 8 contiguous 1KB global_load_lds (source lane-permuted per rule #21).
#define STAGE(DST, XSRC) { \
    _Pragma("unroll") \
    for (int _i = 0; _i < 8; ++_i) \
        __builtin_amdgcn_global_load_lds((GBUF*)((XSRC) + _i * 256 + (lsrc << 2)), \
                                         (LBUF*)((DST) + _i * 256), 16, 0, 0); }

// Per-row constants, numpy-port op order. Hoisted ABOVE all my VMEM so even a
// worst-case VMEM lowering cannot disturb the vmcnt counting below.
#define LOADC(IDX) \
    const int   ch_##IDX  = (wrow + (IDX)) & (C_ - 1); \
    const float w0_##IDX  = w[ch_##IDX * 3 + 0]; \
    const float w1_##IDX  = w[ch_##IDX * 3 + 1]; \
    const float w2_##IDX  = w[ch_##IDX * 3 + 2]; \
    const float bb_##IDX  = cb[ch_##IDX]; \
    const float sq_##IDX  = sqrtf(rvar[ch_##IDX] + 1e-5f); \
    const float rs_##IDX  = 1.0f / sq_##IDX; \
    const float inv_##IDX = gamma[ch_##IDX] * rs_##IDX; \
    const float add_##IDX = beta[ch_##IDX] - rmean[ch_##IDX] * inv_##IDX;

// One pipelined row: stage row IDX+1 (if any), counted wait for row IDX's
// stage, scan (R10 body, bitwise-proven), LDS writeback, coalesced store.
#define DOROW(IDX, WAITN) { \
    float* wl  = ((IDX) & 1) ? buf1 : buf0; \
    float* nxt = ((IDX) & 1) ? buf0 : buf1; \
    if ((IDX) + 1 < NR) { STAGE(nxt, xrow + ((IDX) + 1) * T_) } \
    asm volatile("s_waitcnt vmcnt(" #WAITN ")" ::: "memory"); \
    __builtin_amdgcn_sched_barrier(0); \
    const float w0 = w0_##IDX, w1 = w1_##IDX, w2 = w2_##IDX; \
    const float bb = bb_##IDX, inv = inv_##IDX, add = add_##IDX; \
    float* outr = outrow + (IDX) * T_; \
    const int G2  = 8 * l; \
    const int G1c = (l >= 1) ? G2 - 8  : 0; \
    const int G0c = (l >= 2) ? G2 - 16 : 0; \
    const int gt  = (l >= 3) ? (G2 - 17) : 0; \
    const f32x4 tail = *(const f32x4*)(wl + (swzg(gt) << 2)); \
    float xm1 = (l >= 3) ? tail.w : 0.0f; \
    float v = 0.0f; \
    f32x4 a0,a1,a2,a3,a4,a5,a6,a7; \
    f32x4 b0,b1,b2,b3,b4,b5,b6,b7; \
    f32x4 c0,c1,c2,c3,c4,c5,c6,c7; \
    LDPH(a0,a1,a2,a3,a4,a5,a6,a7, G0c) \
    LDPH(b0,b1,b2,b3,b4,b5,b6,b7, G1c) \
    c0 = *(const f32x4*)(wl + ((G2 + (0 ^ (l & 7))) << 2)); \
    if (l >= 2) { PHC(a0,a1,a2,a3,a4,a5,a6,a7, b0.x) } \
    { \
        const int _m = l & 7; \
        const float* _bp = wl + (G2 << 2); \
        c1 = *(const f32x4*)(_bp + ((1 ^ _m) << 2)); \
        c2 = *(const f32x4*)(_bp + ((2 ^ _m) << 2)); \
        c3 = *(const f32x4*)(_bp + ((3 ^ _m) << 2)); \
        c4 = *(const f32x4*)(_bp + ((4 ^ _m) << 2)); \
        c5 = *(const f32x4*)(_bp + ((5 ^ _m) << 2)); \
        c6 = *(const f32x4*)(_bp + ((6 ^ _m) << 2)); \
        c7 = *(const f32x4*)(_bp + ((7 ^ _m) << 2)); \
    } \
    const int gp = (l < 63) ? (G2 + 8) : 0; \
    const f32x4 pk = *(const f32x4*)(wl + (swzg(gp) << 2)); \
    const float peekOwn = (l == 63) ? 0.0f : pk.x; \
    if (l >= 1) { PHC(b0,b1,b2,b3,b4,b5,b6,b7, c0.x) } \
    f32x4 o0,o1,o2,o3,o4,o5,o6,o7; \
    Q4(c0, c1.x, o0) Q4(c1, c2.x, o1) Q4(c2, c3.x, o2) Q4(c3, c4.x, o3) \
    Q4(c4, c5.x, o4) Q4(c5, c6.x, o5) Q4(c6, c7.x, o6) Q4(c7, peekOwn, o7) \
    { \
        const int m8 = l & 7; \
        float* wb = wl + (G2 << 2); \
        *(f32x4*)(wb + ((0 ^ m8) << 2)) = o0; \
        *(f32x4*)(wb + ((1 ^ m8) << 2)) = o1; \
        *(f32x4*)(wb + ((2 ^ m8) << 2)) = o2; \
        *(f32x4*)(wb + ((3 ^ m8) << 2)) = o3; \
        *(f32x4*)(wb + ((4 ^ m8) << 2)) = o4; \
        *(f32x4*)(wb + ((5 ^ m8) << 2)) = o5; \
        *(f32x4*)(wb + ((6 ^ m8) << 2)) = o6; \
        *(f32x4*)(wb + ((7 ^ m8) << 2)) = o7; \
    } \
    _Pragma("unroll") \
    for (int _i = 0; _i < 8; ++_i) { \
        const f32x4 rb = *(const f32x4*)(wl + ((_i * 64 + lsrc) << 2)); \
        *(f32x4*)(outr + _i * 256 + (l << 2)) = rb; \
    } }

__global__ __launch_bounds__(128, 2) void cpe_lif_kernel(
    const float* __restrict__ x, const float* __restrict__ w,
    const float* __restrict__ cb, const float* __restrict__ gamma,
    const float* __restrict__ beta, const float* __restrict__ rmean,
    const float* __restrict__ rvar, float* __restrict__ out)
{
#pragma clang fp contract(off)   // match np reference rounding op-for-op
    __shared__ __align__(16) float lds[2 * 2 * T_];   // 32 KiB: 2 waves x 2 bufs

    const int tid = threadIdx.x;
    const int wid = __builtin_amdgcn_readfirstlane(tid >> 6);  // provably uniform
    const int l   = tid & 63;

    const int wrow = (blockIdx.x * 2 + wid) * NR;     // 4 consecutive rows/wave
    const float* xrow   = x   + (size_t)wrow * T_;
    float*       outrow = out + (size_t)wrow * T_;

    float* buf0 = lds + wid * 2 * T_;
    float* buf1 = buf0 + T_;

    // All per-row constants first (SMEM; above every VMEM op of ours).
    LOADC(0) LOADC(1) LOADC(2) LOADC(3)

    const int lsrc = l ^ ((l >> 3) & 7);

    STAGE(buf0, xrow)                                  // L0 x8

    // vmcnt FIFO: L0 | L1,S0 | L2,S1 | L3,S2 | S3
    DOROW(0, 8)    // after L1 issued: wait <=8  -> L0 retired
    DOROW(1, 16)   // after L2 issued: wait <=16 -> L1 retired (S0 in flight)
    DOROW(2, 16)   // after L3 issued: wait <=16 -> L2 retired (S1 in flight)
    DOROW(3, 8)    // no stage:        wait <=8  -> L3 retired (S2 in flight)
}

extern "C" void kernel_launch(void* const* d_in, const int* in_sizes, int n_in,
                              void* d_out, int out_size, void* d_ws, size_t ws_size,
                              hipStream_t stream) {
    const float* x     = (const float*)d_in[0];
    const float* w     = (const float*)d_in[1];
    const float* cb    = (const float*)d_in[2];
    const float* gamma = (const float*)d_in[3];
    const float* beta  = (const float*)d_in[4];
    const float* rmean = (const float*)d_in[5];
    const float* rvar  = (const float*)d_in[6];
    float* out = (float*)d_out;

    // 8192 rows / (NR=4 rows/wave) = 2048 waves = 1024 blocks x 2 waves.
    const int grid = (B_ * C_) / (NR * 2);
    cpe_lif_kernel<<<grid, 128, 0, stream>>>(x, w, cb, gamma, beta, rmean, rvar, out);
}

// Round 12
// 30.528 us; speedup vs baseline: 1.0552x; 1.0552x over previous
//
#include <hip/hip_runtime.h>

typedef float f32x4 __attribute__((ext_vector_type(4)));

// Problem constants: x [B,C,T] fp32 -> out [B,C,T] fp32.
#define B_ 32
#define C_ 256
#define T_ 2048
#define NR 4           // rows per wave, pipelined via LOOP (I$-friendly)

// R5:  plain stores (L2 write-combining), never nontemporal.
// R7:  strided global loads cap ~2.6 TB/s -> stage rows via global_load_lds.
// R8:  XOR-swizzled b128 LDS reads conflict-free.
// R9:  residency not the limiter.
// R10: coalesced stores via LDS round-trip: 40->31 us.
// R11: 4x-unrolled pipeline flat at 32 us -> ~40 KB body exceeds 32 KB I$;
//      this round: identical pipeline as a no-unroll loop (~10 KB body).

#define STEP(X0, XP1, O) { \
    float y = w0 * xm1;  y = y + w1 * (X0);  y = y + w2 * (XP1); \
    y = y + bb;  y = y * inv;  y = y + add; \
    float dv = (y - v) * 0.5f;  v = v + dv; \
    float s = (v >= 1.0f) ? 1.0f : 0.0f; \
    (O) = s + (X0); \
    v = (v >= 1.0f) ? 0.0f : v; \
    xm1 = (X0); }

#define Q4(BV, NX, O) \
    STEP(BV.x, BV.y, O.x) STEP(BV.y, BV.z, O.y) \
    STEP(BV.z, BV.w, O.z) STEP(BV.w, NX,   O.w)

#define LDPH(p0,p1,p2,p3,p4,p5,p6,p7, GC) { \
    const int _m = ((GC) >> 3) & 7; \
    const float* _bp = wl + ((GC) << 2); \
    p0 = *(const f32x4*)(_bp + ((0 ^ _m) << 2)); \
    p1 = *(const f32x4*)(_bp + ((1 ^ _m) << 2)); \
    p2 = *(const f32x4*)(_bp + ((2 ^ _m) << 2)); \
    p3 = *(const f32x4*)(_bp + ((3 ^ _m) << 2)); \
    p4 = *(const f32x4*)(_bp + ((4 ^ _m) << 2)); \
    p5 = *(const f32x4*)(_bp + ((5 ^ _m) << 2)); \
    p6 = *(const f32x4*)(_bp + ((6 ^ _m) << 2)); \
    p7 = *(const f32x4*)(_bp + ((7 ^ _m) << 2)); }

#define PHC(r0,r1,r2,r3,r4,r5,r6,r7, PEEK) { \
    f32x4 _d; \
    Q4(r0, r1.x, _d) Q4(r1, r2.x, _d) Q4(r2, r3.x, _d) Q4(r3, r4.x, _d) \
    Q4(r4, r5.x, _d) Q4(r5, r6.x, _d) Q4(r6, r7.x, _d) Q4(r7, (PEEK), _d) }

__device__ __forceinline__ int swzg(int g) { return g ^ ((g >> 3) & 7); }

typedef __attribute__((address_space(1))) const unsigned int GBUF;
typedef __attribute__((address_space(3))) unsigned int LBUF;

// Issue 8 contiguous 1KB global_load_lds (source lane-permuted per rule #21).
#define STAGE(DST, XSRC) { \
    _Pragma("unroll") \
    for (int _i = 0; _i < 8; ++_i) \
        __builtin_amdgcn_global_load_lds((GBUF*)((XSRC) + _i * 256 + (lsrc << 2)), \
                                         (LBUF*)((DST) + _i * 256), 16, 0, 0); }

// Per-row constants, numpy-port op order; hoisted above ALL our VMEM so the
// vmcnt FIFO accounting below is undisturbed even under vector lowering.
#define LOADC(IDX) \
    const int   ch_##IDX  = (wrow + (IDX)) & (C_ - 1); \
    const float w0_##IDX  = w[ch_##IDX * 3 + 0]; \
    const float w1_##IDX  = w[ch_##IDX * 3 + 1]; \
    const float w2_##IDX  = w[ch_##IDX * 3 + 2]; \
    const float bb_##IDX  = cb[ch_##IDX]; \
    const float sq_##IDX  = sqrtf(rvar[ch_##IDX] + 1e-5f); \
    const float rs_##IDX  = 1.0f / sq_##IDX; \
    const float inv_##IDX = gamma[ch_##IDX] * rs_##IDX; \
    const float add_##IDX = beta[ch_##IDX] - rmean[ch_##IDX] * inv_##IDX;

#define SEL4(NAME) ((r == 0) ? NAME##_0 : (r == 1) ? NAME##_1 : \
                    (r == 2) ? NAME##_2 : NAME##_3)

__global__ __launch_bounds__(128, 2) void cpe_lif_kernel(
    const float* __restrict__ x, const float* __restrict__ w,
    const float* __restrict__ cb, const float* __restrict__ gamma,
    const float* __restrict__ beta, const float* __restrict__ rmean,
    const float* __restrict__ rvar, float* __restrict__ out)
{
#pragma clang fp contract(off)   // match np reference rounding op-for-op
    __shared__ __align__(16) float lds[2 * 2 * T_];   // 32 KiB: 2 waves x 2 bufs

    const int tid = threadIdx.x;
    const int wid = __builtin_amdgcn_readfirstlane(tid >> 6);  // uniform
    const int l   = tid & 63;

    const int wrow = (blockIdx.x * 2 + wid) * NR;     // 4 consecutive rows/wave
    const float* xrow   = x   + (size_t)wrow * T_;
    float*       outrow = out + (size_t)wrow * T_;

    float* buf0 = lds + wid * 2 * T_;
    float* buf1 = buf0 + T_;

    LOADC(0) LOADC(1) LOADC(2) LOADC(3)

    const int lsrc = l ^ ((l >> 3) & 7);

    STAGE(buf0, xrow)                                  // L0 x8

    // vmcnt FIFO per iter r (oldest->newest): [L_r, S_{r-1}, L_{r+1}].
    // Need L_r retired: wait 16 steady-state, 8 at r==0 (no S,-) and
    // r==NR-1 (no L_{r+1}). Stores are pinned between successive waits by
    // the asm memory clobbers, so the accounting is order-robust.
#pragma clang loop unroll(disable)
    for (int r = 0; r < NR; ++r) {
        float* wl  = (r & 1) ? buf1 : buf0;
        float* nxt = (r & 1) ? buf0 : buf1;
        if (r + 1 < NR) { STAGE(nxt, xrow + (size_t)(r + 1) * T_) }
        if (r == 0 || r == NR - 1) {
            asm volatile("s_waitcnt vmcnt(8)" ::: "memory");
        } else {
            asm volatile("s_waitcnt vmcnt(16)" ::: "memory");
        }
        __builtin_amdgcn_sched_barrier(0);

        const float w0 = SEL4(w0), w1 = SEL4(w1), w2 = SEL4(w2);
        const float bb = SEL4(bb), inv = SEL4(inv), add = SEL4(add);
        float* outr = outrow + (size_t)r * T_;

        // ---- scan body (R10, bitwise-proven) ----
        const int G2  = 8 * l;
        const int G1c = (l >= 1) ? G2 - 8  : 0;
        const int G0c = (l >= 2) ? G2 - 16 : 0;
        const int gt  = (l >= 3) ? (G2 - 17) : 0;
        const f32x4 tail = *(const f32x4*)(wl + (swzg(gt) << 2));
        float xm1 = (l >= 3) ? tail.w : 0.0f;
        float v = 0.0f;

        f32x4 a0,a1,a2,a3,a4,a5,a6,a7;
        f32x4 b0,b1,b2,b3,b4,b5,b6,b7;
        f32x4 c0,c1,c2,c3,c4,c5,c6,c7;

        LDPH(a0,a1,a2,a3,a4,a5,a6,a7, G0c)
        LDPH(b0,b1,b2,b3,b4,b5,b6,b7, G1c)
        c0 = *(const f32x4*)(wl + ((G2 + (0 ^ (l & 7))) << 2));

        if (l >= 2) { PHC(a0,a1,a2,a3,a4,a5,a6,a7, b0.x) }

        {
            const int _m = l & 7;
            const float* _bp = wl + (G2 << 2);
            c1 = *(const f32x4*)(_bp + ((1 ^ _m) << 2));
            c2 = *(const f32x4*)(_bp + ((2 ^ _m) << 2));
            c3 = *(const f32x4*)(_bp + ((3 ^ _m) << 2));
            c4 = *(const f32x4*)(_bp + ((4 ^ _m) << 2));
            c5 = *(const f32x4*)(_bp + ((5 ^ _m) << 2));
            c6 = *(const f32x4*)(_bp + ((6 ^ _m) << 2));
            c7 = *(const f32x4*)(_bp + ((7 ^ _m) << 2));
        }
        const int gp = (l < 63) ? (G2 + 8) : 0;
        const f32x4 pk = *(const f32x4*)(wl + (swzg(gp) << 2));
        const float peekOwn = (l == 63) ? 0.0f : pk.x;

        if (l >= 1) { PHC(b0,b1,b2,b3,b4,b5,b6,b7, c0.x) }

        f32x4 o0,o1,o2,o3,o4,o5,o6,o7;
        Q4(c0, c1.x, o0) Q4(c1, c2.x, o1) Q4(c2, c3.x, o2) Q4(c3, c4.x, o3)
        Q4(c4, c5.x, o4) Q4(c5, c6.x, o5) Q4(c6, c7.x, o6) Q4(c7, peekOwn, o7)

        {   // LDS writeback (same swzg bijection; wave-private slice)
            const int m8 = l & 7;
            float* wb = wl + (G2 << 2);
            *(f32x4*)(wb + ((0 ^ m8) << 2)) = o0;
            *(f32x4*)(wb + ((1 ^ m8) << 2)) = o1;
            *(f32x4*)(wb + ((2 ^ m8) << 2)) = o2;
            *(f32x4*)(wb + ((3 ^ m8) << 2)) = o3;
            *(f32x4*)(wb + ((4 ^ m8) << 2)) = o4;
            *(f32x4*)(wb + ((5 ^ m8) << 2)) = o5;
            *(f32x4*)(wb + ((6 ^ m8) << 2)) = o6;
            *(f32x4*)(wb + ((7 ^ m8) << 2)) = o7;
        }
        #pragma unroll
        for (int _i = 0; _i < 8; ++_i) {   // coalesced 1 KB stores
            const f32x4 rb = *(const f32x4*)(wl + ((_i * 64 + lsrc) << 2));
            *(f32x4*)(outr + _i * 256 + (l << 2)) = rb;
        }
    }
}

extern "C" void kernel_launch(void* const* d_in, const int* in_sizes, int n_in,
                              void* d_out, int out_size, void* d_ws, size_t ws_size,
                              hipStream_t stream) {
    const float* x     = (const float*)d_in[0];
    const float* w     = (const float*)d_in[1];
    const float* cb    = (const float*)d_in[2];
    const float* gamma = (const float*)d_in[3];
    const float* beta  = (const float*)d_in[4];
    const float* rmean = (const float*)d_in[5];
    const float* rvar  = (const float*)d_in[6];
    float* out = (float*)d_out;

    // 8192 rows / (NR=4 rows/wave) = 2048 waves = 1024 blocks x 2 waves.
    const int grid = (B_ * C_) / (NR * 2);
    cpe_lif_kernel<<<grid, 128, 0, stream>>>(x, w, cb, gamma, beta, rmean, rvar, out);
}